// Round 5
// baseline (1154.085 us; speedup 1.0000x reference)
//
#include <hip/hip_runtime.h>
#include <math.h>

#define NN 10000
#define NE 640000
#define H 128
#define H2 256
#define XD 8
#define ED 8
#define YD 112
#define NL 4
#define EPS_MSG 1e-7f
#define EPS_SM 1e-16f
#define EPS_LN 1e-5f
#define TN 16
#define TEB 128   // edges per tile (NE = 5000 * TEB exactly)

// ---------- CSR build ----------
__global__ void hist_k(const int* __restrict__ dst, int* __restrict__ counts) {
    int e = blockIdx.x * 256 + threadIdx.x;
    if (e < NE) atomicAdd(&counts[dst[e]], 1);
}

__global__ void scan_k(const int* __restrict__ counts, int* __restrict__ rowptr) {
    __shared__ int part[1024];
    int tid = threadIdx.x;
    const int CH = (NN + 1023) / 1024;  // 10
    int base = tid * CH;
    int s = 0;
    for (int j = 0; j < CH; j++) { int i = base + j; if (i < NN) s += counts[i]; }
    part[tid] = s; __syncthreads();
    for (int off = 1; off < 1024; off <<= 1) {
        int v = (tid >= off) ? part[tid - off] : 0;
        __syncthreads();
        part[tid] += v;
        __syncthreads();
    }
    int run = part[tid] - s;  // exclusive prefix
    for (int j = 0; j < CH; j++) {
        int i = base + j;
        if (i < NN) { rowptr[i] = run; run += counts[i]; }
    }
    if (tid == 1023) rowptr[NN] = run;  // == NE
}

__global__ void scatter_k(const int* __restrict__ src, const int* __restrict__ dst,
                          const float* __restrict__ eattr, const int* __restrict__ rowptr,
                          int* __restrict__ fill, int* __restrict__ srcs,
                          int* __restrict__ dsts, float* __restrict__ eacsr) {
    int e = blockIdx.x * 256 + threadIdx.x;
    if (e >= NE) return;
    int d = dst[e];
    int pos = rowptr[d] + atomicAdd(&fill[d], 1);
    srcs[pos] = src[e];
    dsts[pos] = d;
    const float4* ein = (const float4*)eattr;
    float4* eout = (float4*)eacsr;
    eout[(size_t)pos * 2]     = ein[(size_t)e * 2];
    eout[(size_t)pos * 2 + 1] = ein[(size_t)e * 2 + 1];
}

// ---------- node encoder: h = x @ Wn + bn ----------
__global__ void node_enc_k(const float* __restrict__ x, const float* __restrict__ Wn,
                           const float* __restrict__ bn, float* __restrict__ h) {
    int n = blockIdx.x, c = threadIdx.x;
    __shared__ float xl[XD];
    if (c < XD) xl[c] = x[n * XD + c];
    __syncthreads();
    float acc = bn[c];
#pragma unroll
    for (int k = 0; k < XD; k++) acc = fmaf(xl[k], Wn[k * H + c], acc);
    h[(size_t)n * H + c] = acc;
}

// ---------- edge-tiled segment sums: den/num via atomic flush on dst change ----------
__global__ void __launch_bounds__(256) edge_agg_k(
    const float* __restrict__ rin, const int* __restrict__ dsts,
    const int* __restrict__ srcs, const float* __restrict__ eacsr,
    const float* __restrict__ We, const float* __restrict__ be,
    const float* __restrict__ tptr, int layer,
    float* __restrict__ deng, float* __restrict__ numg) {
    int tid = threadIdx.x;
    int c = tid & 127;            // channel
    int slot = tid >> 7;          // 0,1
    int tile = blockIdx.x * 2 + slot;
    int j0 = tile * TEB;

    float wc[ED];
#pragma unroll
    for (int k = 0; k < ED; k++) wc[k] = We[k * H + c];
    float bec = be[c];
    float ts2 = tptr[layer] * 1.44269504088896f;  // t * log2(e)

    float den = 0.f, num = 0.f;
    int cur = dsts[j0];
    for (int jj = 0; jj < TEB; jj++) {
        int j = j0 + jj;
        int d = dsts[j];
        if (d != cur) {
            atomicAdd(&deng[(size_t)cur * H + c], den);
            atomicAdd(&numg[(size_t)cur * H + c], num);
            den = 0.f; num = 0.f; cur = d;
        }
        int sn = srcs[j];
        float4 e0 = *(const float4*)(eacsr + (size_t)j * ED);
        float4 e1 = *(const float4*)(eacsr + (size_t)j * ED + 4);
        float hv = rin[(size_t)sn * H + c];
        float p = bec;
        p = fmaf(e0.x, wc[0], p); p = fmaf(e0.y, wc[1], p);
        p = fmaf(e0.z, wc[2], p); p = fmaf(e0.w, wc[3], p);
        p = fmaf(e1.x, wc[4], p); p = fmaf(e1.y, wc[5], p);
        p = fmaf(e1.z, wc[6], p); p = fmaf(e1.w, wc[7], p);
        float msg = fmaxf(hv + p, 0.f) + EPS_MSG;
        float pe = __builtin_amdgcn_exp2f(msg * ts2);
        den += pe;
        num = fmaf(pe, msg, num);
    }
    atomicAdd(&deng[(size_t)cur * H + c], den);
    atomicAdd(&numg[(size_t)cur * H + c], num);
}

// ---------- y1 = agg @ W1[i] + b1[i]  (agg = num/(den+eps) + rin, fused) ----------
__global__ void __launch_bounds__(256) mm1_k(const float* __restrict__ rin,
    const float* __restrict__ deng, const float* __restrict__ numg,
    const float* __restrict__ W1i, const float* __restrict__ b1i,
    float* __restrict__ y1, float* __restrict__ part) {
    int nb = blockIdx.x, o = threadIdx.x;
    int n0 = nb * TN;
    __shared__ float a[TN][H];
    for (int t = o; t < TN * H; t += 256) {
        size_t idx = (size_t)n0 * H + t;
        ((float*)a)[t] = numg[idx] / (deng[idx] + EPS_SM) + rin[idx];
    }
    __syncthreads();
    float acc[TN];
#pragma unroll
    for (int i = 0; i < TN; i++) acc[i] = 0.f;
    for (int k = 0; k < H; k++) {
        float w = W1i[k * H2 + o];
#pragma unroll
        for (int i = 0; i < TN; i++) acc[i] = fmaf(a[i][k], w, acc[i]);
    }
    float bo = b1i[o];
    float ps = 0.f, ps2 = 0.f;
#pragma unroll
    for (int i = 0; i < TN; i++) {
        float v = acc[i] + bo;
        y1[(size_t)(n0 + i) * H2 + o] = v;
        ps += v; ps2 += v * v;
    }
#pragma unroll
    for (int off = 32; off; off >>= 1) { ps += __shfl_xor(ps, off); ps2 += __shfl_xor(ps2, off); }
    __shared__ float red[8];
    int w = o >> 6;
    if ((o & 63) == 0) { red[w] = ps; red[4 + w] = ps2; }
    __syncthreads();
    if (o == 0) {
        part[nb * 2]     = red[0] + red[1] + red[2] + red[3];
        part[nb * 2 + 1] = red[4] + red[5] + red[6] + red[7];
    }
}

// ---------- graph-LN stats finalize ----------
__global__ void stats_k(const float* __restrict__ part, int nb, float* __restrict__ stats) {
    int tid = threadIdx.x;  // 256
    float s = 0.f, s2 = 0.f;
    for (int i = tid; i < nb; i += 256) { s += part[2 * i]; s2 += part[2 * i + 1]; }
#pragma unroll
    for (int off = 32; off; off >>= 1) { s += __shfl_xor(s, off); s2 += __shfl_xor(s2, off); }
    __shared__ float red[8];
    int w = tid >> 6;
    if ((tid & 63) == 0) { red[w] = s; red[4 + w] = s2; }
    __syncthreads();
    if (tid == 0) {
        float S = red[0] + red[1] + red[2] + red[3];
        float S2 = red[4] + red[5] + red[6] + red[7];
        const float M = (float)NN * (float)H2;
        float m = S / M;
        float var = fmaxf(S2 / M - m * m, 0.f);
        stats[0] = m;
        stats[1] = 1.f / (sqrtf(var) + EPS_LN);
    }
}

// ---------- z = relu(graph_ln(y1)); h (+)= z @ W2[i] + b2[i]; r = relu(node_ln(h)) ----------
__global__ void __launch_bounds__(128) mm2_k(const float* __restrict__ y1,
    const float* __restrict__ g1i, const float* __restrict__ bt1i,
    const float* __restrict__ W2i, const float* __restrict__ b2i,
    const float* __restrict__ stats, float* __restrict__ h,
    const float* __restrict__ lgp, const float* __restrict__ lbp,
    float* __restrict__ r, int first) {
    int nb = blockIdx.x, o = threadIdx.x;
    int n0 = nb * TN;
    __shared__ float z[TN][H2];  // 16 KiB
    float m = stats[0], istd = stats[1];
    for (int t = o; t < TN * H2; t += 128) {
        int k = t & 255;
        float v = y1[(size_t)n0 * H2 + t];
        v = (v - m) * istd * g1i[k] + bt1i[k];
        ((float*)z)[t] = fmaxf(v, 0.f);
    }
    __syncthreads();
    float acc[TN];
#pragma unroll
    for (int i = 0; i < TN; i++) acc[i] = 0.f;
    for (int k = 0; k < H2; k++) {
        float w = W2i[k * H + o];
#pragma unroll
        for (int i = 0; i < TN; i++) acc[i] = fmaf(z[i][k], w, acc[i]);
    }
    float bo = b2i[o];
    float vv[TN];
#pragma unroll
    for (int i = 0; i < TN; i++) {
        size_t idx = (size_t)(n0 + i) * H + o;
        float v = acc[i] + bo;
        if (!first) v += h[idx];
        h[idx] = v;
        vv[i] = v;
    }
    // fused node-LN + ReLU -> r
    __shared__ float rs[2][TN], rs2[2][TN];
    int w = o >> 6;
#pragma unroll
    for (int i = 0; i < TN; i++) {
        float s = vv[i], s2 = vv[i] * vv[i];
#pragma unroll
        for (int off = 32; off; off >>= 1) { s += __shfl_xor(s, off); s2 += __shfl_xor(s2, off); }
        if ((o & 63) == 0) { rs[w][i] = s; rs2[w][i] = s2; }
    }
    __syncthreads();
    float gc = lgp[o], bc = lbp[o];
#pragma unroll
    for (int i = 0; i < TN; i++) {
        float S = rs[0][i] + rs[1][i], S2 = rs2[0][i] + rs2[1][i];
        float mn = S * (1.f / H);
        float var = S2 * (1.f / H) - mn * mn;
        float inv = rsqrtf(var + EPS_LN);
        float ov = (vv[i] - mn) * inv * gc + bc;
        r[(size_t)(n0 + i) * H + o] = fmaxf(ov, 0.f);
    }
}

// ---------- out = r @ Wout + bout ----------
__global__ void __launch_bounds__(128) mmout_k(const float* __restrict__ r,
    const float* __restrict__ Wout, const float* __restrict__ bout,
    float* __restrict__ out) {
    int nb = blockIdx.x, o = threadIdx.x;
    int n0 = nb * TN;
    __shared__ float a[TN][H];
    for (int t = o; t < TN * H; t += 128) ((float*)a)[t] = r[(size_t)n0 * H + t];
    __syncthreads();
    if (o < YD) {
        float acc[TN];
#pragma unroll
        for (int i = 0; i < TN; i++) acc[i] = 0.f;
        for (int k = 0; k < H; k++) {
            float w = Wout[k * YD + o];
#pragma unroll
            for (int i = 0; i < TN; i++) acc[i] = fmaf(a[i][k], w, acc[i]);
        }
        float bo = bout[o];
#pragma unroll
        for (int i = 0; i < TN; i++) out[(size_t)(n0 + i) * YD + o] = acc[i] + bo;
    }
}

extern "C" void kernel_launch(void* const* d_in, const int* in_sizes, int n_in,
                              void* d_out, int out_size, void* d_ws, size_t ws_size,
                              hipStream_t stream) {
    const float* x    = (const float*)d_in[0];
    const int*   ei   = (const int*)d_in[1];
    const float* eattr= (const float*)d_in[2];
    const float* Wn   = (const float*)d_in[3];
    const float* bn   = (const float*)d_in[4];
    const float* We   = (const float*)d_in[5];
    const float* be   = (const float*)d_in[6];
    const float* t    = (const float*)d_in[7];
    const float* W1   = (const float*)d_in[8];
    const float* b1   = (const float*)d_in[9];
    const float* g1   = (const float*)d_in[10];
    const float* bt1  = (const float*)d_in[11];
    const float* W2   = (const float*)d_in[12];
    const float* b2   = (const float*)d_in[13];
    const float* lng  = (const float*)d_in[14];
    const float* lnb  = (const float*)d_in[15];
    const float* Wout = (const float*)d_in[16];
    const float* bout = (const float*)d_in[17];
    float* out = (float*)d_out;

    const int* src = ei;        // edge_index[0]
    const int* dst = ei + NE;   // edge_index[1]

    char* ws = (char*)d_ws;
    size_t off = 0;
    auto alloc = [&](size_t bytes) -> char* {
        char* p = ws + off;
        off += (bytes + 255) & ~(size_t)255;
        return p;
    };
    int*   counts = (int*)alloc((size_t)NN * 4);
    int*   fill   = (int*)alloc((size_t)NN * 4);
    int*   rowptr = (int*)alloc((size_t)(NN + 1) * 4);
    int*   srcs   = (int*)alloc((size_t)NE * 4);
    int*   dsts   = (int*)alloc((size_t)NE * 4);
    float* eacsr  = (float*)alloc((size_t)NE * ED * 4);  // 20 MB
    float* dennum = (float*)alloc((size_t)NN * H * 2 * 4);  // den | num, contiguous
    float* deng   = dennum;
    float* numg   = dennum + (size_t)NN * H;
    float* h      = (float*)alloc((size_t)NN * H * 4);
    float* r      = (float*)alloc((size_t)NN * H * 4);
    float* y1     = (float*)alloc((size_t)NN * H2 * 4);
    const int NB1 = NN / TN;  // 625 (exact)
    float* part   = (float*)alloc((size_t)NB1 * 2 * 4);
    float* stats  = (float*)alloc(2 * 4);
    (void)ws_size; (void)in_sizes; (void)n_in; (void)out_size;

    hipMemsetAsync(counts, 0, (size_t)NN * 4, stream);
    hipMemsetAsync(fill,   0, (size_t)NN * 4, stream);

    hist_k<<<(NE + 255) / 256, 256, 0, stream>>>(dst, counts);
    scan_k<<<1, 1024, 0, stream>>>(counts, rowptr);
    scatter_k<<<(NE + 255) / 256, 256, 0, stream>>>(src, dst, eattr, rowptr, fill,
                                                    srcs, dsts, eacsr);
    node_enc_k<<<NN, H, 0, stream>>>(x, Wn, bn, h);

    const int NTILE = NE / TEB;  // 5000
    for (int i = 0; i < NL; i++) {
        const float* cin = (i == 0) ? h : r;
        hipMemsetAsync(dennum, 0, (size_t)NN * H * 2 * 4, stream);
        edge_agg_k<<<NTILE / 2, 256, 0, stream>>>(cin, dsts, srcs, eacsr, We, be, t, i,
                                                  deng, numg);
        mm1_k<<<NB1, 256, 0, stream>>>(cin, deng, numg,
                                       W1 + (size_t)i * H * H2, b1 + i * H2, y1, part);
        stats_k<<<1, 256, 0, stream>>>(part, NB1, stats);
        int nx = (i == NL - 1) ? 0 : (i + 1);  // next node-LN params (final uses layer 0's)
        mm2_k<<<NB1, 128, 0, stream>>>(y1, g1 + i * H2, bt1 + i * H2,
                                       W2 + (size_t)i * H2 * H, b2 + i * H, stats, h,
                                       lng + nx * H, lnb + nx * H, r, (i == 0) ? 1 : 0);
    }
    mmout_k<<<NB1, 128, 0, stream>>>(r, Wout, bout, out);
}

// Round 6
// 790.592 us; speedup vs baseline: 1.4598x; 1.4598x over previous
//
#include <hip/hip_runtime.h>
#include <math.h>

#define NN 10000
#define NE 640000
#define H 128
#define H2 256
#define XD 8
#define ED 8
#define YD 112
#define NL 4
#define EPS_MSG 1e-7f
#define EPS_SM 1e-16f
#define EPS_LN 1e-5f
#define TN 16
#define NB1 (NN / TN)   // 625

// ---------- CSR build ----------
__global__ void hist_k(const int* __restrict__ dst, int* __restrict__ counts) {
    int e = blockIdx.x * 256 + threadIdx.x;
    if (e < NE) atomicAdd(&counts[dst[e]], 1);
}

__global__ void scan_k(const int* __restrict__ counts, int* __restrict__ rowptr) {
    __shared__ int part[1024];
    int tid = threadIdx.x;
    const int CH = (NN + 1023) / 1024;  // 10
    int base = tid * CH;
    int s = 0;
    for (int j = 0; j < CH; j++) { int i = base + j; if (i < NN) s += counts[i]; }
    part[tid] = s; __syncthreads();
    for (int off = 1; off < 1024; off <<= 1) {
        int v = (tid >= off) ? part[tid - off] : 0;
        __syncthreads();
        part[tid] += v;
        __syncthreads();
    }
    int run = part[tid] - s;  // exclusive prefix
    for (int j = 0; j < CH; j++) {
        int i = base + j;
        if (i < NN) { rowptr[i] = run; run += counts[i]; }
    }
    if (tid == 1023) rowptr[NN] = run;  // == NE
}

__global__ void scatter_k(const int* __restrict__ src, const int* __restrict__ dst,
                          const float* __restrict__ eattr, const int* __restrict__ rowptr,
                          int* __restrict__ fill, int* __restrict__ srcs,
                          float* __restrict__ eacsr) {
    int e = blockIdx.x * 256 + threadIdx.x;
    if (e >= NE) return;
    int d = dst[e];
    int pos = rowptr[d] + atomicAdd(&fill[d], 1);
    srcs[pos] = src[e];
    const float4* ein = (const float4*)eattr;
    float4* eout = (float4*)eacsr;
    eout[(size_t)pos * 2]     = ein[(size_t)e * 2];
    eout[(size_t)pos * 2 + 1] = ein[(size_t)e * 2 + 1];
}

// ---------- node encoder: h = x @ Wn + bn ----------
__global__ void node_enc_k(const float* __restrict__ x, const float* __restrict__ Wn,
                           const float* __restrict__ bn, float* __restrict__ h) {
    int n = blockIdx.x, c = threadIdx.x;
    __shared__ float xl[XD];
    if (c < XD) xl[c] = x[n * XD + c];
    __syncthreads();
    float acc = bn[c];
#pragma unroll
    for (int k = 0; k < XD; k++) acc = fmaf(xl[k], Wn[k * H + c], acc);
    h[(size_t)n * H + c] = acc;
}

// ---------- per-node edge aggregation: lane owns (n,c); no LDS, no barriers ----------
__global__ void __launch_bounds__(128) edge_agg_k(
    const float* __restrict__ rin, const int* __restrict__ rowptr,
    const int* __restrict__ srcs, const float* __restrict__ eacsr,
    const float* __restrict__ We, const float* __restrict__ be,
    const float* __restrict__ tptr, int layer, float* __restrict__ agg) {
    int n = blockIdx.x, c = threadIdx.x;
    float wc[ED];
#pragma unroll
    for (int k = 0; k < ED; k++) wc[k] = We[k * H + c];
    float bec = be[c];
    float ts2 = tptr[layer] * 1.44269504088896f;  // t * log2(e)
    int beg = rowptr[n], end = rowptr[n + 1];
    float rv = rin[(size_t)n * H + c];
    float den = 0.f, num = 0.f;
#pragma unroll 4
    for (int j = beg; j < end; ++j) {
        int sn = srcs[j];                                  // wave-uniform load
        float4 e0 = *(const float4*)(eacsr + (size_t)j * ED);      // wave-uniform
        float4 e1 = *(const float4*)(eacsr + (size_t)j * ED + 4);  // wave-uniform
        float hv = rin[(size_t)sn * H + c];                // coalesced gather
        float p = bec;
        p = fmaf(e0.x, wc[0], p); p = fmaf(e0.y, wc[1], p);
        p = fmaf(e0.z, wc[2], p); p = fmaf(e0.w, wc[3], p);
        p = fmaf(e1.x, wc[4], p); p = fmaf(e1.y, wc[5], p);
        p = fmaf(e1.z, wc[6], p); p = fmaf(e1.w, wc[7], p);
        float msg = fmaxf(hv + p, 0.f) + EPS_MSG;
        float pe = __builtin_amdgcn_exp2f(msg * ts2);
        den += pe;
        num = fmaf(pe, msg, num);
    }
    agg[(size_t)n * H + c] = num / (den + EPS_SM) + rv;
}

// ---------- y1 = agg @ W1[i] + b1[i]; last block finalizes graph-LN stats ----------
__global__ void __launch_bounds__(256) mm1_k(const float* __restrict__ agg,
    const float* __restrict__ W1i, const float* __restrict__ b1i,
    float* __restrict__ y1, float* __restrict__ part,
    int* __restrict__ ctr, float* __restrict__ stats) {
    int nb = blockIdx.x, o = threadIdx.x;
    int n0 = nb * TN;
    __shared__ float a[TN][H];
    for (int t = o; t < TN * H; t += 256) ((float*)a)[t] = agg[(size_t)n0 * H + t];
    __syncthreads();
    float acc[TN];
#pragma unroll
    for (int i = 0; i < TN; i++) acc[i] = 0.f;
    for (int k = 0; k < H; k++) {
        float w = W1i[k * H2 + o];
#pragma unroll
        for (int i = 0; i < TN; i++) acc[i] = fmaf(a[i][k], w, acc[i]);
    }
    float bo = b1i[o];
    float ps = 0.f, ps2 = 0.f;
#pragma unroll
    for (int i = 0; i < TN; i++) {
        float v = acc[i] + bo;
        y1[(size_t)(n0 + i) * H2 + o] = v;
        ps += v; ps2 += v * v;
    }
#pragma unroll
    for (int off = 32; off; off >>= 1) { ps += __shfl_xor(ps, off); ps2 += __shfl_xor(ps2, off); }
    __shared__ float red[8];
    int w = o >> 6;
    if ((o & 63) == 0) { red[w] = ps; red[4 + w] = ps2; }
    __syncthreads();
    if (o == 0) {
        part[nb * 2]     = red[0] + red[1] + red[2] + red[3];
        part[nb * 2 + 1] = red[4] + red[5] + red[6] + red[7];
    }
    // last-block-finishes pattern: reduce all partials -> stats (deterministic sum order)
    __shared__ int lastfl;
    __threadfence();
    if (o == 0) lastfl = (atomicAdd(ctr, 1) == NB1 - 1) ? 1 : 0;
    __syncthreads();
    if (lastfl) {
        float s = 0.f, s2 = 0.f;
        for (int i = o; i < NB1; i += 256) { s += part[2 * i]; s2 += part[2 * i + 1]; }
#pragma unroll
        for (int off = 32; off; off >>= 1) { s += __shfl_xor(s, off); s2 += __shfl_xor(s2, off); }
        __syncthreads();  // red[] reuse
        if ((o & 63) == 0) { red[w] = s; red[4 + w] = s2; }
        __syncthreads();
        if (o == 0) {
            float S = red[0] + red[1] + red[2] + red[3];
            float S2 = red[4] + red[5] + red[6] + red[7];
            const float M = (float)NN * (float)H2;
            float m = S / M;
            float var = fmaxf(S2 / M - m * m, 0.f);
            stats[0] = m;
            stats[1] = 1.f / (sqrtf(var) + EPS_LN);
        }
    }
}

// ---------- z = relu(graph_ln(y1)); h (+)= z @ W2[i] + b2[i]; r = relu(node_ln(h)) ----------
__global__ void __launch_bounds__(128) mm2_k(const float* __restrict__ y1,
    const float* __restrict__ g1i, const float* __restrict__ bt1i,
    const float* __restrict__ W2i, const float* __restrict__ b2i,
    const float* __restrict__ stats, float* __restrict__ h,
    const float* __restrict__ lgp, const float* __restrict__ lbp,
    float* __restrict__ r, int first) {
    int nb = blockIdx.x, o = threadIdx.x;
    int n0 = nb * TN;
    __shared__ float z[TN][H2];  // 16 KiB
    float m = stats[0], istd = stats[1];
    for (int t = o; t < TN * H2; t += 128) {
        int k = t & 255;
        float v = y1[(size_t)n0 * H2 + t];
        v = (v - m) * istd * g1i[k] + bt1i[k];
        ((float*)z)[t] = fmaxf(v, 0.f);
    }
    __syncthreads();
    float acc[TN];
#pragma unroll
    for (int i = 0; i < TN; i++) acc[i] = 0.f;
    for (int k = 0; k < H2; k++) {
        float w = W2i[k * H + o];
#pragma unroll
        for (int i = 0; i < TN; i++) acc[i] = fmaf(z[i][k], w, acc[i]);
    }
    float bo = b2i[o];
    float vv[TN];
#pragma unroll
    for (int i = 0; i < TN; i++) {
        size_t idx = (size_t)(n0 + i) * H + o;
        float v = acc[i] + bo;
        if (!first) v += h[idx];
        h[idx] = v;
        vv[i] = v;
    }
    // fused node-LN + ReLU -> r
    __shared__ float rs[2][TN], rs2[2][TN];
    int w = o >> 6;
#pragma unroll
    for (int i = 0; i < TN; i++) {
        float s = vv[i], s2 = vv[i] * vv[i];
#pragma unroll
        for (int off = 32; off; off >>= 1) { s += __shfl_xor(s, off); s2 += __shfl_xor(s2, off); }
        if ((o & 63) == 0) { rs[w][i] = s; rs2[w][i] = s2; }
    }
    __syncthreads();
    float gc = lgp[o], bc = lbp[o];
#pragma unroll
    for (int i = 0; i < TN; i++) {
        float S = rs[0][i] + rs[1][i], S2 = rs2[0][i] + rs2[1][i];
        float mn = S * (1.f / H);
        float var = S2 * (1.f / H) - mn * mn;
        float inv = rsqrtf(var + EPS_LN);
        float ov = (vv[i] - mn) * inv * gc + bc;
        r[(size_t)(n0 + i) * H + o] = fmaxf(ov, 0.f);
    }
}

// ---------- out = r @ Wout + bout ----------
__global__ void __launch_bounds__(128) mmout_k(const float* __restrict__ r,
    const float* __restrict__ Wout, const float* __restrict__ bout,
    float* __restrict__ out) {
    int nb = blockIdx.x, o = threadIdx.x;
    int n0 = nb * TN;
    __shared__ float a[TN][H];
    for (int t = o; t < TN * H; t += 128) ((float*)a)[t] = r[(size_t)n0 * H + t];
    __syncthreads();
    if (o < YD) {
        float acc[TN];
#pragma unroll
        for (int i = 0; i < TN; i++) acc[i] = 0.f;
        for (int k = 0; k < H; k++) {
            float w = Wout[k * YD + o];
#pragma unroll
            for (int i = 0; i < TN; i++) acc[i] = fmaf(a[i][k], w, acc[i]);
        }
        float bo = bout[o];
#pragma unroll
        for (int i = 0; i < TN; i++) out[(size_t)(n0 + i) * YD + o] = acc[i] + bo;
    }
}

extern "C" void kernel_launch(void* const* d_in, const int* in_sizes, int n_in,
                              void* d_out, int out_size, void* d_ws, size_t ws_size,
                              hipStream_t stream) {
    const float* x    = (const float*)d_in[0];
    const int*   ei   = (const int*)d_in[1];
    const float* eattr= (const float*)d_in[2];
    const float* Wn   = (const float*)d_in[3];
    const float* bn   = (const float*)d_in[4];
    const float* We   = (const float*)d_in[5];
    const float* be   = (const float*)d_in[6];
    const float* t    = (const float*)d_in[7];
    const float* W1   = (const float*)d_in[8];
    const float* b1   = (const float*)d_in[9];
    const float* g1   = (const float*)d_in[10];
    const float* bt1  = (const float*)d_in[11];
    const float* W2   = (const float*)d_in[12];
    const float* b2   = (const float*)d_in[13];
    const float* lng  = (const float*)d_in[14];
    const float* lnb  = (const float*)d_in[15];
    const float* Wout = (const float*)d_in[16];
    const float* bout = (const float*)d_in[17];
    float* out = (float*)d_out;

    const int* src = ei;        // edge_index[0]
    const int* dst = ei + NE;   // edge_index[1]

    char* ws = (char*)d_ws;
    size_t off = 0;
    auto alloc = [&](size_t bytes) -> char* {
        char* p = ws + off;
        off += (bytes + 255) & ~(size_t)255;
        return p;
    };
    int*   counts = (int*)alloc((size_t)NN * 4);
    int*   fill   = (int*)alloc((size_t)NN * 4);
    int*   rowptr = (int*)alloc((size_t)(NN + 1) * 4);
    int*   srcs   = (int*)alloc((size_t)NE * 4);
    float* eacsr  = (float*)alloc((size_t)NE * ED * 4);  // 20 MB
    float* h      = (float*)alloc((size_t)NN * H * 4);
    float* r      = (float*)alloc((size_t)NN * H * 4);
    float* agg    = (float*)alloc((size_t)NN * H * 4);
    float* y1     = (float*)alloc((size_t)NN * H2 * 4);
    float* part   = (float*)alloc((size_t)NB1 * 2 * 4);
    float* stats  = (float*)alloc(2 * 4);
    int*   ctrs   = (int*)alloc(NL * 4);
    (void)ws_size; (void)in_sizes; (void)n_in; (void)out_size;

    hipMemsetAsync(counts, 0, (size_t)NN * 4, stream);
    hipMemsetAsync(fill,   0, (size_t)NN * 4, stream);
    hipMemsetAsync(ctrs,   0, (size_t)NL * 4, stream);

    hist_k<<<(NE + 255) / 256, 256, 0, stream>>>(dst, counts);
    scan_k<<<1, 1024, 0, stream>>>(counts, rowptr);
    scatter_k<<<(NE + 255) / 256, 256, 0, stream>>>(src, dst, eattr, rowptr, fill,
                                                    srcs, eacsr);
    node_enc_k<<<NN, H, 0, stream>>>(x, Wn, bn, h);

    for (int i = 0; i < NL; i++) {
        const float* cin = (i == 0) ? h : r;
        edge_agg_k<<<NN, H, 0, stream>>>(cin, rowptr, srcs, eacsr, We, be, t, i, agg);
        mm1_k<<<NB1, 256, 0, stream>>>(agg, W1 + (size_t)i * H * H2, b1 + i * H2,
                                       y1, part, ctrs + i, stats);
        int nx = (i == NL - 1) ? 0 : (i + 1);  // next node-LN params (final uses layer 0's)
        mm2_k<<<NB1, 128, 0, stream>>>(y1, g1 + i * H2, bt1 + i * H2,
                                       W2 + (size_t)i * H2 * H, b2 + i * H, stats, h,
                                       lng + nx * H, lnb + nx * H, r, (i == 0) ? 1 : 0);
    }
    mmout_k<<<NB1, 128, 0, stream>>>(r, Wout, bout, out);
}

// Round 7
// 580.056 us; speedup vs baseline: 1.9896x; 1.3630x over previous
//
#include <hip/hip_runtime.h>
#include <math.h>

#define NN 10000
#define NE 640000
#define H 128
#define H2 256
#define XD 8
#define ED 8
#define YD 112
#define NL 4
#define EPS_MSG 1e-7f
#define EPS_SM 1e-16f
#define EPS_LN 1e-5f
#define TN 16
#define NB1 (NN / TN)   // 625

// ---------- CSR build ----------
__global__ void hist_k(const int* __restrict__ dst, int* __restrict__ counts) {
    int e = blockIdx.x * 256 + threadIdx.x;
    if (e < NE) atomicAdd(&counts[dst[e]], 1);
}

__global__ void scan_k(const int* __restrict__ counts, int* __restrict__ rowptr) {
    __shared__ int part[1024];
    int tid = threadIdx.x;
    const int CH = (NN + 1023) / 1024;  // 10
    int base = tid * CH;
    int s = 0;
    for (int j = 0; j < CH; j++) { int i = base + j; if (i < NN) s += counts[i]; }
    part[tid] = s; __syncthreads();
    for (int off = 1; off < 1024; off <<= 1) {
        int v = (tid >= off) ? part[tid - off] : 0;
        __syncthreads();
        part[tid] += v;
        __syncthreads();
    }
    int run = part[tid] - s;  // exclusive prefix
    for (int j = 0; j < CH; j++) {
        int i = base + j;
        if (i < NN) { rowptr[i] = run; run += counts[i]; }
    }
    if (tid == 1023) rowptr[NN] = run;  // == NE
}

__global__ void scatter_k(const int* __restrict__ src, const int* __restrict__ dst,
                          const float* __restrict__ eattr, const int* __restrict__ rowptr,
                          int* __restrict__ fill, int* __restrict__ srcs,
                          _Float16* __restrict__ eacsr) {
    int e = blockIdx.x * 256 + threadIdx.x;
    if (e >= NE) return;
    int d = dst[e];
    int pos = rowptr[d] + atomicAdd(&fill[d], 1);
    srcs[pos] = src[e];
    const float4* ein = (const float4*)eattr;
    float4 a = ein[(size_t)e * 2];
    float4 b = ein[(size_t)e * 2 + 1];
    float4 pack;
    _Float16* pp = (_Float16*)&pack;
    pp[0] = (_Float16)a.x; pp[1] = (_Float16)a.y; pp[2] = (_Float16)a.z; pp[3] = (_Float16)a.w;
    pp[4] = (_Float16)b.x; pp[5] = (_Float16)b.y; pp[6] = (_Float16)b.z; pp[7] = (_Float16)b.w;
    ((float4*)eacsr)[pos] = pack;   // one 16 B store
}

// ---------- node encoder: h = x @ Wn + bn ----------
__global__ void node_enc_k(const float* __restrict__ x, const float* __restrict__ Wn,
                           const float* __restrict__ bn, float* __restrict__ h) {
    int n = blockIdx.x, c = threadIdx.x;
    __shared__ float xl[XD];
    if (c < XD) xl[c] = x[n * XD + c];
    __syncthreads();
    float acc = bn[c];
#pragma unroll
    for (int k = 0; k < XD; k++) acc = fmaf(xl[k], Wn[k * H + c], acc);
    h[(size_t)n * H + c] = acc;
}

// ---------- per-node edge aggregation: lane owns (n,c); no LDS, no barriers ----------
__global__ void __launch_bounds__(128) edge_agg_k(
    const float* __restrict__ rin, const int* __restrict__ rowptr,
    const int* __restrict__ srcs, const _Float16* __restrict__ eacsr,
    const float* __restrict__ We, const float* __restrict__ be,
    const float* __restrict__ tptr, int layer, float* __restrict__ agg) {
    int n = blockIdx.x, c = threadIdx.x;
    float wc[ED];
#pragma unroll
    for (int k = 0; k < ED; k++) wc[k] = We[k * H + c];
    float bec = be[c];
    float ts2 = tptr[layer] * 1.44269504088896f;  // t * log2(e)
    int beg = rowptr[n], end = rowptr[n + 1];
    float rv = rin[(size_t)n * H + c];
    float den = 0.f, num = 0.f;
#pragma unroll 4
    for (int j = beg; j < end; ++j) {
        int sn = srcs[j];
        float4 raw = *(const float4*)(eacsr + (size_t)j * ED);  // 8 halves, one dwordx4
        const _Float16* ep = (const _Float16*)&raw;
        float hv = rin[(size_t)sn * H + c];                     // coalesced gather
        float p = bec;
        p = fmaf((float)ep[0], wc[0], p); p = fmaf((float)ep[1], wc[1], p);
        p = fmaf((float)ep[2], wc[2], p); p = fmaf((float)ep[3], wc[3], p);
        p = fmaf((float)ep[4], wc[4], p); p = fmaf((float)ep[5], wc[5], p);
        p = fmaf((float)ep[6], wc[6], p); p = fmaf((float)ep[7], wc[7], p);
        float msg = fmaxf(hv + p, 0.f) + EPS_MSG;
        float pe = __builtin_amdgcn_exp2f(msg * ts2);
        den += pe;
        num = fmaf(pe, msg, num);
    }
    agg[(size_t)n * H + c] = num / (den + EPS_SM) + rv;
}

// ---------- y1 = agg @ W1[i] + b1[i], plus deterministic partial sums ----------
__global__ void __launch_bounds__(256) mm1_k(const float* __restrict__ agg,
    const float* __restrict__ W1i, const float* __restrict__ b1i,
    float* __restrict__ y1, float* __restrict__ part) {
    int nb = blockIdx.x, o = threadIdx.x;
    int n0 = nb * TN;
    __shared__ float a[TN][H];
    for (int t = o; t < TN * H; t += 256) ((float*)a)[t] = agg[(size_t)n0 * H + t];
    __syncthreads();
    float acc[TN];
#pragma unroll
    for (int i = 0; i < TN; i++) acc[i] = 0.f;
    for (int k = 0; k < H; k++) {
        float w = W1i[k * H2 + o];
#pragma unroll
        for (int i = 0; i < TN; i++) acc[i] = fmaf(a[i][k], w, acc[i]);
    }
    float bo = b1i[o];
    float ps = 0.f, ps2 = 0.f;
#pragma unroll
    for (int i = 0; i < TN; i++) {
        float v = acc[i] + bo;
        y1[(size_t)(n0 + i) * H2 + o] = v;
        ps += v; ps2 += v * v;
    }
#pragma unroll
    for (int off = 32; off; off >>= 1) { ps += __shfl_xor(ps, off); ps2 += __shfl_xor(ps2, off); }
    __shared__ float red[8];
    int w = o >> 6;
    if ((o & 63) == 0) { red[w] = ps; red[4 + w] = ps2; }
    __syncthreads();
    if (o == 0) {
        part[nb * 2]     = red[0] + red[1] + red[2] + red[3];
        part[nb * 2 + 1] = red[4] + red[5] + red[6] + red[7];
    }
}

// ---------- z = relu(graph_ln(y1)); h (+)= z @ W2[i] + b2[i]; r = relu(node_ln(h)) ----------
// graph-LN stats recomputed per block from part[] (5 KB, L2-hit, deterministic).
__global__ void __launch_bounds__(128) mm2_k(const float* __restrict__ y1,
    const float* __restrict__ g1i, const float* __restrict__ bt1i,
    const float* __restrict__ W2i, const float* __restrict__ b2i,
    const float* __restrict__ part, float* __restrict__ h,
    const float* __restrict__ lgp, const float* __restrict__ lbp,
    float* __restrict__ r, int first) {
    int nb = blockIdx.x, o = threadIdx.x;
    int n0 = nb * TN;
    // ---- stats from partials (identical, fixed order in every block) ----
    float s = 0.f, s2 = 0.f;
    for (int i = o; i < NB1; i += 128) { s += part[2 * i]; s2 += part[2 * i + 1]; }
#pragma unroll
    for (int off = 32; off; off >>= 1) { s += __shfl_xor(s, off); s2 += __shfl_xor(s2, off); }
    __shared__ float sred[4];
    int w = o >> 6;
    if ((o & 63) == 0) { sred[w] = s; sred[2 + w] = s2; }
    __syncthreads();
    const float M = (float)NN * (float)H2;
    float m = (sred[0] + sred[1]) / M;
    float var = fmaxf((sred[2] + sred[3]) / M - m * m, 0.f);
    float istd = 1.f / (sqrtf(var) + EPS_LN);
    __syncthreads();

    __shared__ float z[TN][H2];  // 16 KiB
    for (int t = o; t < TN * H2; t += 128) {
        int k = t & 255;
        float v = y1[(size_t)n0 * H2 + t];
        v = (v - m) * istd * g1i[k] + bt1i[k];
        ((float*)z)[t] = fmaxf(v, 0.f);
    }
    __syncthreads();
    float acc[TN];
#pragma unroll
    for (int i = 0; i < TN; i++) acc[i] = 0.f;
    for (int k = 0; k < H2; k++) {
        float wv = W2i[k * H + o];
#pragma unroll
        for (int i = 0; i < TN; i++) acc[i] = fmaf(z[i][k], wv, acc[i]);
    }
    float bo = b2i[o];
    float vv[TN];
#pragma unroll
    for (int i = 0; i < TN; i++) {
        size_t idx = (size_t)(n0 + i) * H + o;
        float v = acc[i] + bo;
        if (!first) v += h[idx];
        h[idx] = v;
        vv[i] = v;
    }
    // fused node-LN + ReLU -> r
    __shared__ float rs[2][TN], rs2[2][TN];
#pragma unroll
    for (int i = 0; i < TN; i++) {
        float ss = vv[i], ss2 = vv[i] * vv[i];
#pragma unroll
        for (int off = 32; off; off >>= 1) { ss += __shfl_xor(ss, off); ss2 += __shfl_xor(ss2, off); }
        if ((o & 63) == 0) { rs[w][i] = ss; rs2[w][i] = ss2; }
    }
    __syncthreads();
    float gc = lgp[o], bc = lbp[o];
#pragma unroll
    for (int i = 0; i < TN; i++) {
        float S = rs[0][i] + rs[1][i], S2 = rs2[0][i] + rs2[1][i];
        float mn = S * (1.f / H);
        float vr = S2 * (1.f / H) - mn * mn;
        float inv = rsqrtf(vr + EPS_LN);
        float ov = (vv[i] - mn) * inv * gc + bc;
        r[(size_t)(n0 + i) * H + o] = fmaxf(ov, 0.f);
    }
}

// ---------- out = r @ Wout + bout ----------
__global__ void __launch_bounds__(128) mmout_k(const float* __restrict__ r,
    const float* __restrict__ Wout, const float* __restrict__ bout,
    float* __restrict__ out) {
    int nb = blockIdx.x, o = threadIdx.x;
    int n0 = nb * TN;
    __shared__ float a[TN][H];
    for (int t = o; t < TN * H; t += 128) ((float*)a)[t] = r[(size_t)n0 * H + t];
    __syncthreads();
    if (o < YD) {
        float acc[TN];
#pragma unroll
        for (int i = 0; i < TN; i++) acc[i] = 0.f;
        for (int k = 0; k < H; k++) {
            float w = Wout[k * YD + o];
#pragma unroll
            for (int i = 0; i < TN; i++) acc[i] = fmaf(a[i][k], w, acc[i]);
        }
        float bo = bout[o];
#pragma unroll
        for (int i = 0; i < TN; i++) out[(size_t)(n0 + i) * YD + o] = acc[i] + bo;
    }
}

extern "C" void kernel_launch(void* const* d_in, const int* in_sizes, int n_in,
                              void* d_out, int out_size, void* d_ws, size_t ws_size,
                              hipStream_t stream) {
    const float* x    = (const float*)d_in[0];
    const int*   ei   = (const int*)d_in[1];
    const float* eattr= (const float*)d_in[2];
    const float* Wn   = (const float*)d_in[3];
    const float* bn   = (const float*)d_in[4];
    const float* We   = (const float*)d_in[5];
    const float* be   = (const float*)d_in[6];
    const float* t    = (const float*)d_in[7];
    const float* W1   = (const float*)d_in[8];
    const float* b1   = (const float*)d_in[9];
    const float* g1   = (const float*)d_in[10];
    const float* bt1  = (const float*)d_in[11];
    const float* W2   = (const float*)d_in[12];
    const float* b2   = (const float*)d_in[13];
    const float* lng  = (const float*)d_in[14];
    const float* lnb  = (const float*)d_in[15];
    const float* Wout = (const float*)d_in[16];
    const float* bout = (const float*)d_in[17];
    float* out = (float*)d_out;

    const int* src = ei;        // edge_index[0]
    const int* dst = ei + NE;   // edge_index[1]

    char* ws = (char*)d_ws;
    size_t off = 0;
    auto alloc = [&](size_t bytes) -> char* {
        char* p = ws + off;
        off += (bytes + 255) & ~(size_t)255;
        return p;
    };
    int*      counts = (int*)alloc((size_t)NN * 4);
    int*      fill   = (int*)alloc((size_t)NN * 4);
    int*      rowptr = (int*)alloc((size_t)(NN + 1) * 4);
    int*      srcs   = (int*)alloc((size_t)NE * 4);
    _Float16* eacsr  = (_Float16*)alloc((size_t)NE * ED * 2);  // 10 MB fp16
    float*    h      = (float*)alloc((size_t)NN * H * 4);
    float*    r      = (float*)alloc((size_t)NN * H * 4);
    float*    agg    = (float*)alloc((size_t)NN * H * 4);
    float*    y1     = (float*)alloc((size_t)NN * H2 * 4);
    float*    part   = (float*)alloc((size_t)NB1 * 2 * 4);
    (void)ws_size; (void)in_sizes; (void)n_in; (void)out_size;

    hipMemsetAsync(counts, 0, (size_t)NN * 4, stream);
    hipMemsetAsync(fill,   0, (size_t)NN * 4, stream);

    hist_k<<<(NE + 255) / 256, 256, 0, stream>>>(dst, counts);
    scan_k<<<1, 1024, 0, stream>>>(counts, rowptr);
    scatter_k<<<(NE + 255) / 256, 256, 0, stream>>>(src, dst, eattr, rowptr, fill,
                                                    srcs, eacsr);
    node_enc_k<<<NN, H, 0, stream>>>(x, Wn, bn, h);

    for (int i = 0; i < NL; i++) {
        const float* cin = (i == 0) ? h : r;
        edge_agg_k<<<NN, H, 0, stream>>>(cin, rowptr, srcs, eacsr, We, be, t, i, agg);
        mm1_k<<<NB1, 256, 0, stream>>>(agg, W1 + (size_t)i * H * H2, b1 + i * H2, y1, part);
        int nx = (i == NL - 1) ? 0 : (i + 1);  // next node-LN params (final uses layer 0's)
        mm2_k<<<NB1, 128, 0, stream>>>(y1, g1 + i * H2, bt1 + i * H2,
                                       W2 + (size_t)i * H2 * H, b2 + i * H, part, h,
                                       lng + nx * H, lnb + nx * H, r, (i == 0) ? 1 : 0);
    }
    mmout_k<<<NB1, 128, 0, stream>>>(r, Wout, bout, out);
}

// Round 9
// 490.919 us; speedup vs baseline: 2.3509x; 1.1816x over previous
//
#include <hip/hip_runtime.h>
#include <math.h>

#define NN 10000
#define NE 640000
#define H 128
#define H2 256
#define XD 8
#define ED 8
#define YD 112
#define NL 4
#define EPS_MSG 1e-7f
#define EPS_SM 1e-16f
#define EPS_LN 1e-5f
#define TM 8
#define NB1 (NN / TM)    // 1250 (mm1/mm2 blocks)
#define TNO 16
#define NBO (NN / TNO)   // 625 (mmout blocks)

// ---------- CSR build ----------
__global__ void hist_k(const int* __restrict__ dst, int* __restrict__ counts) {
    int e = blockIdx.x * 256 + threadIdx.x;
    if (e < NE) atomicAdd(&counts[dst[e]], 1);
}

__global__ void scan_k(const int* __restrict__ counts, int* __restrict__ rowptr) {
    __shared__ int part[1024];
    int tid = threadIdx.x;
    const int CH = (NN + 1023) / 1024;  // 10
    int base = tid * CH;
    int s = 0;
    for (int j = 0; j < CH; j++) { int i = base + j; if (i < NN) s += counts[i]; }
    part[tid] = s; __syncthreads();
    for (int off = 1; off < 1024; off <<= 1) {
        int v = (tid >= off) ? part[tid - off] : 0;
        __syncthreads();
        part[tid] += v;
        __syncthreads();
    }
    int run = part[tid] - s;  // exclusive prefix
    for (int j = 0; j < CH; j++) {
        int i = base + j;
        if (i < NN) { rowptr[i] = run; run += counts[i]; }
    }
    if (tid == 1023) rowptr[NN] = run;  // == NE
}

__global__ void scatter_k(const int* __restrict__ src, const int* __restrict__ dst,
                          const float* __restrict__ eattr, const int* __restrict__ rowptr,
                          int* __restrict__ fill, int* __restrict__ srcs,
                          _Float16* __restrict__ eacsr) {
    int e = blockIdx.x * 256 + threadIdx.x;
    if (e >= NE) return;
    int d = dst[e];
    int pos = rowptr[d] + atomicAdd(&fill[d], 1);
    srcs[pos] = src[e];
    const float4* ein = (const float4*)eattr;
    float4 a = ein[(size_t)e * 2];
    float4 b = ein[(size_t)e * 2 + 1];
    float4 pack;
    _Float16* pp = (_Float16*)&pack;
    pp[0] = (_Float16)a.x; pp[1] = (_Float16)a.y; pp[2] = (_Float16)a.z; pp[3] = (_Float16)a.w;
    pp[4] = (_Float16)b.x; pp[5] = (_Float16)b.y; pp[6] = (_Float16)b.z; pp[7] = (_Float16)b.w;
    ((float4*)eacsr)[pos] = pack;   // one 16 B store
}

// ---------- node encoder: h = x @ Wn + bn ----------
__global__ void node_enc_k(const float* __restrict__ x, const float* __restrict__ Wn,
                           const float* __restrict__ bn, float* __restrict__ h) {
    int n = blockIdx.x, c = threadIdx.x;
    __shared__ float xl[XD];
    if (c < XD) xl[c] = x[n * XD + c];
    __syncthreads();
    float acc = bn[c];
#pragma unroll
    for (int k = 0; k < XD; k++) acc = fmaf(xl[k], Wn[k * H + c], acc);
    h[(size_t)n * H + c] = acc;
}

// ---------- per-node edge aggregation: lane owns (n,c); no LDS, no barriers ----------
__global__ void __launch_bounds__(128) edge_agg_k(
    const float* __restrict__ rin, const int* __restrict__ rowptr,
    const int* __restrict__ srcs, const _Float16* __restrict__ eacsr,
    const float* __restrict__ We, const float* __restrict__ be,
    const float* __restrict__ tptr, int layer, float* __restrict__ agg) {
    int n = blockIdx.x, c = threadIdx.x;
    float wc[ED];
#pragma unroll
    for (int k = 0; k < ED; k++) wc[k] = We[k * H + c];
    float bec = be[c];
    float ts2 = tptr[layer] * 1.44269504088896f;  // t * log2(e)
    int beg = rowptr[n], end = rowptr[n + 1];
    float rv = rin[(size_t)n * H + c];
    float den = 0.f, num = 0.f;
#pragma unroll 4
    for (int j = beg; j < end; ++j) {
        int sn = srcs[j];
        float4 raw = *(const float4*)(eacsr + (size_t)j * ED);  // 8 halves, one dwordx4
        const _Float16* ep = (const _Float16*)&raw;
        float hv = rin[(size_t)sn * H + c];                     // coalesced gather
        float p = bec;
        p = fmaf((float)ep[0], wc[0], p); p = fmaf((float)ep[1], wc[1], p);
        p = fmaf((float)ep[2], wc[2], p); p = fmaf((float)ep[3], wc[3], p);
        p = fmaf((float)ep[4], wc[4], p); p = fmaf((float)ep[5], wc[5], p);
        p = fmaf((float)ep[6], wc[6], p); p = fmaf((float)ep[7], wc[7], p);
        float msg = fmaxf(hv + p, 0.f) + EPS_MSG;
        float pe = __builtin_amdgcn_exp2f(msg * ts2);
        den += pe;
        num = fmaf(pe, msg, num);
    }
    agg[(size_t)n * H + c] = num / (den + EPS_SM) + rv;
}

// ---------- y1 = agg @ W1[i] + b1[i], plus deterministic partial sums ----------
__global__ void __launch_bounds__(256) mm1_k(const float* __restrict__ agg,
    const float* __restrict__ W1i, const float* __restrict__ b1i,
    float* __restrict__ y1, float* __restrict__ part) {
    int nb = blockIdx.x, o = threadIdx.x;  // o = output channel (256)
    int n0 = nb * TM;
    __shared__ float a[TM][H];  // 4 KB
    for (int t = o; t < TM * H; t += 256) ((float*)a)[t] = agg[(size_t)n0 * H + t];
    __syncthreads();
    float acc[TM];
#pragma unroll
    for (int i = 0; i < TM; i++) acc[i] = 0.f;
    for (int k = 0; k < H; k++) {
        float w = W1i[k * H2 + o];
#pragma unroll
        for (int i = 0; i < TM; i++) acc[i] = fmaf(a[i][k], w, acc[i]);
    }
    float bo = b1i[o];
    float ps = 0.f, ps2 = 0.f;
#pragma unroll
    for (int i = 0; i < TM; i++) {
        float v = acc[i] + bo;
        y1[(size_t)(n0 + i) * H2 + o] = v;
        ps += v; ps2 += v * v;
    }
#pragma unroll
    for (int off = 32; off; off >>= 1) { ps += __shfl_xor(ps, off); ps2 += __shfl_xor(ps2, off); }
    __shared__ float red[8];
    int w = o >> 6;
    if ((o & 63) == 0) { red[w] = ps; red[4 + w] = ps2; }
    __syncthreads();
    if (o == 0) {
        part[nb * 2]     = red[0] + red[1] + red[2] + red[3];
        part[nb * 2 + 1] = red[4] + red[5] + red[6] + red[7];
    }
}

// ---------- z = relu(graph_ln(y1)); h (+)= z @ W2[i] + b2[i]; r = relu(node_ln(h)) ----------
// Row-split: 256 threads; half = tid>>7 owns 4 of the block's 8 rows; o = tid&127.
// Per-row math identical to the proven round-7 kernel; halves share only the z tile.
__global__ void __launch_bounds__(256) mm2_k(const float* __restrict__ y1,
    const float* __restrict__ g1i, const float* __restrict__ bt1i,
    const float* __restrict__ W2i, const float* __restrict__ b2i,
    const float* __restrict__ part, float* __restrict__ h,
    const float* __restrict__ lgp, const float* __restrict__ lbp,
    float* __restrict__ r, int first) {
    int nb = blockIdx.x, tid = threadIdx.x;
    int o = tid & 127, half = tid >> 7;
    int rb = half * 4;             // this half's first local row
    int n0 = nb * TM;
    // ---- graph-LN stats from partials (identical fixed order in every block) ----
    float s = 0.f, s2 = 0.f;
    for (int i = tid; i < NB1; i += 256) { s += part[2 * i]; s2 += part[2 * i + 1]; }
#pragma unroll
    for (int off = 32; off; off >>= 1) { s += __shfl_xor(s, off); s2 += __shfl_xor(s2, off); }
    __shared__ float sred[8];
    int w4 = tid >> 6;
    if ((tid & 63) == 0) { sred[w4] = s; sred[4 + w4] = s2; }
    __syncthreads();
    const float M = (float)NN * (float)H2;
    float m = (sred[0] + sred[1] + sred[2] + sred[3]) / M;
    float var = fmaxf((sred[4] + sred[5] + sred[6] + sred[7]) / M - m * m, 0.f);
    float istd = 1.f / (sqrtf(var) + EPS_LN);

    __shared__ float z[TM][H2];  // 8 KB
    __syncthreads();
    for (int t = tid; t < TM * H2; t += 256) {
        int k = t & 255;
        float v = y1[(size_t)n0 * H2 + t];
        v = (v - m) * istd * g1i[k] + bt1i[k];
        ((float*)z)[t] = fmaxf(v, 0.f);
    }
    __syncthreads();
    float acc[4];
#pragma unroll
    for (int i = 0; i < 4; i++) acc[i] = 0.f;
    for (int k = 0; k < H2; k++) {
        float wv = W2i[k * H + o];
#pragma unroll
        for (int i = 0; i < 4; i++) acc[i] = fmaf(z[rb + i][k], wv, acc[i]);
    }
    float bo = b2i[o];
    float vv[4];
#pragma unroll
    for (int i = 0; i < 4; i++) {
        size_t idx = (size_t)(n0 + rb + i) * H + o;
        float v = acc[i] + bo;
        if (!first) v += h[idx];
        h[idx] = v;
        vv[i] = v;
    }
    // fused node-LN + ReLU -> r  (each half reduces its own rows over its own 2 waves)
    __shared__ float rs[2][2][4], rs2[2][2][4];
    int w2 = (tid >> 6) & 1;       // wave within half
#pragma unroll
    for (int i = 0; i < 4; i++) {
        float ss = vv[i], ss2 = vv[i] * vv[i];
#pragma unroll
        for (int off = 32; off; off >>= 1) { ss += __shfl_xor(ss, off); ss2 += __shfl_xor(ss2, off); }
        if ((tid & 63) == 0) { rs[half][w2][i] = ss; rs2[half][w2][i] = ss2; }
    }
    __syncthreads();
    float gc = lgp[o], bc = lbp[o];
#pragma unroll
    for (int i = 0; i < 4; i++) {
        float S = rs[half][0][i] + rs[half][1][i];
        float S2 = rs2[half][0][i] + rs2[half][1][i];
        float mn = S * (1.f / H);
        float vr = S2 * (1.f / H) - mn * mn;
        float inv = rsqrtf(vr + EPS_LN);
        float ov = (vv[i] - mn) * inv * gc + bc;
        r[(size_t)(n0 + rb + i) * H + o] = fmaxf(ov, 0.f);
    }
}

// ---------- out = r @ Wout + bout ----------
__global__ void __launch_bounds__(128) mmout_k(const float* __restrict__ r,
    const float* __restrict__ Wout, const float* __restrict__ bout,
    float* __restrict__ out) {
    int nb = blockIdx.x, o = threadIdx.x;
    int n0 = nb * TNO;
    __shared__ float a[TNO][H];
    for (int t = o; t < TNO * H; t += 128) ((float*)a)[t] = r[(size_t)n0 * H + t];
    __syncthreads();
    if (o < YD) {
        float acc[TNO];
#pragma unroll
        for (int i = 0; i < TNO; i++) acc[i] = 0.f;
        for (int k = 0; k < H; k++) {
            float w = Wout[k * YD + o];
#pragma unroll
            for (int i = 0; i < TNO; i++) acc[i] = fmaf(a[i][k], w, acc[i]);
        }
        float bo = bout[o];
#pragma unroll
        for (int i = 0; i < TNO; i++) out[(size_t)(n0 + i) * YD + o] = acc[i] + bo;
    }
}

extern "C" void kernel_launch(void* const* d_in, const int* in_sizes, int n_in,
                              void* d_out, int out_size, void* d_ws, size_t ws_size,
                              hipStream_t stream) {
    const float* x    = (const float*)d_in[0];
    const int*   ei   = (const int*)d_in[1];
    const float* eattr= (const float*)d_in[2];
    const float* Wn   = (const float*)d_in[3];
    const float* bn   = (const float*)d_in[4];
    const float* We   = (const float*)d_in[5];
    const float* be   = (const float*)d_in[6];
    const float* t    = (const float*)d_in[7];
    const float* W1   = (const float*)d_in[8];
    const float* b1   = (const float*)d_in[9];
    const float* g1   = (const float*)d_in[10];
    const float* bt1  = (const float*)d_in[11];
    const float* W2   = (const float*)d_in[12];
    const float* b2   = (const float*)d_in[13];
    const float* lng  = (const float*)d_in[14];
    const float* lnb  = (const float*)d_in[15];
    const float* Wout = (const float*)d_in[16];
    const float* bout = (const float*)d_in[17];
    float* out = (float*)d_out;

    const int* src = ei;        // edge_index[0]
    const int* dst = ei + NE;   // edge_index[1]

    char* ws = (char*)d_ws;
    size_t off = 0;
    auto alloc = [&](size_t bytes) -> char* {
        char* p = ws + off;
        off += (bytes + 255) & ~(size_t)255;
        return p;
    };
    int*      counts = (int*)alloc((size_t)NN * 4);
    int*      fill   = (int*)alloc((size_t)NN * 4);
    int*      rowptr = (int*)alloc((size_t)(NN + 1) * 4);
    int*      srcs   = (int*)alloc((size_t)NE * 4);
    _Float16* eacsr  = (_Float16*)alloc((size_t)NE * ED * 2);  // 10 MB fp16
    float*    h      = (float*)alloc((size_t)NN * H * 4);
    float*    r      = (float*)alloc((size_t)NN * H * 4);
    float*    agg    = (float*)alloc((size_t)NN * H * 4);
    float*    y1     = (float*)alloc((size_t)NN * H2 * 4);
    float*    part   = (float*)alloc((size_t)NB1 * 2 * 4);
    (void)ws_size; (void)in_sizes; (void)n_in; (void)out_size;

    hipMemsetAsync(counts, 0, (size_t)NN * 4, stream);
    hipMemsetAsync(fill,   0, (size_t)NN * 4, stream);

    hist_k<<<(NE + 255) / 256, 256, 0, stream>>>(dst, counts);
    scan_k<<<1, 1024, 0, stream>>>(counts, rowptr);
    scatter_k<<<(NE + 255) / 256, 256, 0, stream>>>(src, dst, eattr, rowptr, fill,
                                                    srcs, eacsr);
    node_enc_k<<<NN, H, 0, stream>>>(x, Wn, bn, h);

    for (int i = 0; i < NL; i++) {
        const float* cin = (i == 0) ? h : r;
        edge_agg_k<<<NN, H, 0, stream>>>(cin, rowptr, srcs, eacsr, We, be, t, i, agg);
        mm1_k<<<NB1, 256, 0, stream>>>(agg, W1 + (size_t)i * H * H2, b1 + i * H2, y1, part);
        int nx = (i == NL - 1) ? 0 : (i + 1);  // next node-LN params (final uses layer 0's)
        mm2_k<<<NB1, 256, 0, stream>>>(y1, g1 + i * H2, bt1 + i * H2,
                                       W2 + (size_t)i * H2 * H, b2 + i * H, part, h,
                                       lng + nx * H, lnb + nx * H, r, (i == 0) ? 1 : 0);
    }
    mmout_k<<<NBO, 128, 0, stream>>>(r, Wout, bout, out);
}

// Round 10
// 489.698 us; speedup vs baseline: 2.3567x; 1.0025x over previous
//
#include <hip/hip_runtime.h>
#include <math.h>

#define NN 10000
#define NE 640000
#define H 128
#define H2 256
#define XD 8
#define ED 8
#define YD 112
#define NL 4
#define EPS_MSG 1e-7f
#define EPS_SM 1e-16f
#define EPS_LN 1e-5f
#define TM 8
#define NB1 (NN / TM)    // 1250 (mm1/mm2 blocks)
#define TNO 16
#define NBO (NN / TNO)   // 625 (mmout blocks)

typedef _Float16 h2 __attribute__((ext_vector_type(2)));

// ---------- CSR build ----------
__global__ void hist_k(const int* __restrict__ dst, int* __restrict__ counts) {
    int e = blockIdx.x * 256 + threadIdx.x;
    if (e < NE) atomicAdd(&counts[dst[e]], 1);
}

__global__ void scan_k(const int* __restrict__ counts, int* __restrict__ rowptr) {
    __shared__ int part[1024];
    int tid = threadIdx.x;
    const int CH = (NN + 1023) / 1024;  // 10
    int base = tid * CH;
    int s = 0;
    for (int j = 0; j < CH; j++) { int i = base + j; if (i < NN) s += counts[i]; }
    part[tid] = s; __syncthreads();
    for (int off = 1; off < 1024; off <<= 1) {
        int v = (tid >= off) ? part[tid - off] : 0;
        __syncthreads();
        part[tid] += v;
        __syncthreads();
    }
    int run = part[tid] - s;  // exclusive prefix
    for (int j = 0; j < CH; j++) {
        int i = base + j;
        if (i < NN) { rowptr[i] = run; run += counts[i]; }
    }
    if (tid == 1023) rowptr[NN] = run;  // == NE
}

// pass 1: perm[pos] = e  (random 4B writes into 2.5 MB, L2-resident)
__global__ void scatter_k(const int* __restrict__ dst, const int* __restrict__ rowptr,
                          int* __restrict__ fill, int* __restrict__ perm) {
    int e = blockIdx.x * 256 + threadIdx.x;
    if (e >= NE) return;
    int d = dst[e];
    int pos = rowptr[d] + atomicAdd(&fill[d], 1);
    perm[pos] = e;
}

// pass 2: sequential write of srcs + fp16 eacsr; random reads of src/eattr (L2/L3)
__global__ void pack_k(const int* __restrict__ perm, const int* __restrict__ src,
                       const float* __restrict__ eattr, int* __restrict__ srcs,
                       _Float16* __restrict__ eacsr) {
    int pos = blockIdx.x * 256 + threadIdx.x;
    if (pos >= NE) return;
    int e = perm[pos];
    srcs[pos] = src[e];
    const float4* ein = (const float4*)eattr;
    float4 a = ein[(size_t)e * 2];
    float4 b = ein[(size_t)e * 2 + 1];
    float4 pack;
    _Float16* pp = (_Float16*)&pack;
    pp[0] = (_Float16)a.x; pp[1] = (_Float16)a.y; pp[2] = (_Float16)a.z; pp[3] = (_Float16)a.w;
    pp[4] = (_Float16)b.x; pp[5] = (_Float16)b.y; pp[6] = (_Float16)b.z; pp[7] = (_Float16)b.w;
    ((float4*)eacsr)[pos] = pack;   // coalesced 16 B store
}

// ---------- node encoder: h = x @ Wn + bn ----------
__global__ void node_enc_k(const float* __restrict__ x, const float* __restrict__ Wn,
                           const float* __restrict__ bn, float* __restrict__ h) {
    int n = blockIdx.x, c = threadIdx.x;
    __shared__ float xl[XD];
    if (c < XD) xl[c] = x[n * XD + c];
    __syncthreads();
    float acc = bn[c];
#pragma unroll
    for (int k = 0; k < XD; k++) acc = fmaf(xl[k], Wn[k * H + c], acc);
    h[(size_t)n * H + c] = acc;
}

// ---------- per-node edge aggregation: lane owns (n,c); fdot2 projection ----------
__global__ void __launch_bounds__(128) edge_agg_k(
    const float* __restrict__ rin, const int* __restrict__ rowptr,
    const int* __restrict__ srcs, const _Float16* __restrict__ eacsr,
    const float* __restrict__ We, const float* __restrict__ be,
    const float* __restrict__ tptr, int layer, float* __restrict__ agg) {
    int n = blockIdx.x, c = threadIdx.x;
    h2 w01, w23, w45, w67;
    {
        float f0 = We[0 * H + c], f1 = We[1 * H + c], f2 = We[2 * H + c], f3 = We[3 * H + c];
        float f4 = We[4 * H + c], f5 = We[5 * H + c], f6 = We[6 * H + c], f7 = We[7 * H + c];
        w01[0] = (_Float16)f0; w01[1] = (_Float16)f1;
        w23[0] = (_Float16)f2; w23[1] = (_Float16)f3;
        w45[0] = (_Float16)f4; w45[1] = (_Float16)f5;
        w67[0] = (_Float16)f6; w67[1] = (_Float16)f7;
    }
    float bec = be[c];
    float ts2 = tptr[layer] * 1.44269504088896f;  // t * log2(e)
    int beg = rowptr[n], end = rowptr[n + 1];
    float rv = rin[(size_t)n * H + c];
    float den = 0.f, num = 0.f;
#pragma unroll 4
    for (int j = beg; j < end; ++j) {
        int sn = srcs[j];
        float4 raw = *(const float4*)(eacsr + (size_t)j * ED);  // 8 halves
        const h2* ep = (const h2*)&raw;
        float hv = rin[(size_t)sn * H + c];                     // coalesced gather
        float p = __builtin_amdgcn_fdot2(ep[0], w01, bec, false);
        p = __builtin_amdgcn_fdot2(ep[1], w23, p, false);
        p = __builtin_amdgcn_fdot2(ep[2], w45, p, false);
        p = __builtin_amdgcn_fdot2(ep[3], w67, p, false);
        float msg = fmaxf(hv + p, 0.f) + EPS_MSG;
        float pe = __builtin_amdgcn_exp2f(msg * ts2);
        den += pe;
        num = fmaf(pe, msg, num);
    }
    agg[(size_t)n * H + c] = num / (den + EPS_SM) + rv;
}

// ---------- y1 = agg @ W1[i] + b1[i], plus deterministic partial sums ----------
__global__ void __launch_bounds__(256) mm1_k(const float* __restrict__ agg,
    const float* __restrict__ W1i, const float* __restrict__ b1i,
    float* __restrict__ y1, float* __restrict__ part) {
    int nb = blockIdx.x, o = threadIdx.x;  // o = output channel (256)
    int n0 = nb * TM;
    __shared__ float a[TM][H];  // 4 KB
    for (int t = o; t < TM * H; t += 256) ((float*)a)[t] = agg[(size_t)n0 * H + t];
    __syncthreads();
    float acc[TM];
#pragma unroll
    for (int i = 0; i < TM; i++) acc[i] = 0.f;
    for (int k = 0; k < H; k++) {
        float w = W1i[k * H2 + o];
#pragma unroll
        for (int i = 0; i < TM; i++) acc[i] = fmaf(a[i][k], w, acc[i]);
    }
    float bo = b1i[o];
    float ps = 0.f, ps2 = 0.f;
#pragma unroll
    for (int i = 0; i < TM; i++) {
        float v = acc[i] + bo;
        y1[(size_t)(n0 + i) * H2 + o] = v;
        ps += v; ps2 += v * v;
    }
#pragma unroll
    for (int off = 32; off; off >>= 1) { ps += __shfl_xor(ps, off); ps2 += __shfl_xor(ps2, off); }
    __shared__ float red[8];
    int w = o >> 6;
    if ((o & 63) == 0) { red[w] = ps; red[4 + w] = ps2; }
    __syncthreads();
    if (o == 0) {
        part[nb * 2]     = red[0] + red[1] + red[2] + red[3];
        part[nb * 2 + 1] = red[4] + red[5] + red[6] + red[7];
    }
}

// ---------- z = relu(graph_ln(y1)); h (+)= z @ W2[i] + b2[i]; r = relu(node_ln(h)) ----------
// Row-split: 256 threads; half = tid>>7 owns 4 of the block's 8 rows; o = tid&127.
__global__ void __launch_bounds__(256) mm2_k(const float* __restrict__ y1,
    const float* __restrict__ g1i, const float* __restrict__ bt1i,
    const float* __restrict__ W2i, const float* __restrict__ b2i,
    const float* __restrict__ part, float* __restrict__ h,
    const float* __restrict__ lgp, const float* __restrict__ lbp,
    float* __restrict__ r, int first) {
    int nb = blockIdx.x, tid = threadIdx.x;
    int o = tid & 127, half = tid >> 7;
    int rb = half * 4;             // this half's first local row
    int n0 = nb * TM;
    // ---- graph-LN stats from partials (identical fixed order in every block) ----
    float s = 0.f, s2 = 0.f;
    for (int i = tid; i < NB1; i += 256) { s += part[2 * i]; s2 += part[2 * i + 1]; }
#pragma unroll
    for (int off = 32; off; off >>= 1) { s += __shfl_xor(s, off); s2 += __shfl_xor(s2, off); }
    __shared__ float sred[8];
    int w4 = tid >> 6;
    if ((tid & 63) == 0) { sred[w4] = s; sred[4 + w4] = s2; }
    __syncthreads();
    const float M = (float)NN * (float)H2;
    float m = (sred[0] + sred[1] + sred[2] + sred[3]) / M;
    float var = fmaxf((sred[4] + sred[5] + sred[6] + sred[7]) / M - m * m, 0.f);
    float istd = 1.f / (sqrtf(var) + EPS_LN);

    __shared__ float z[TM][H2];  // 8 KB
    __syncthreads();
    for (int t = tid; t < TM * H2; t += 256) {
        int k = t & 255;
        float v = y1[(size_t)n0 * H2 + t];
        v = (v - m) * istd * g1i[k] + bt1i[k];
        ((float*)z)[t] = fmaxf(v, 0.f);
    }
    __syncthreads();
    float acc[4];
#pragma unroll
    for (int i = 0; i < 4; i++) acc[i] = 0.f;
    for (int k = 0; k < H2; k++) {
        float wv = W2i[k * H + o];
#pragma unroll
        for (int i = 0; i < 4; i++) acc[i] = fmaf(z[rb + i][k], wv, acc[i]);
    }
    float bo = b2i[o];
    float vv[4];
#pragma unroll
    for (int i = 0; i < 4; i++) {
        size_t idx = (size_t)(n0 + rb + i) * H + o;
        float v = acc[i] + bo;
        if (!first) v += h[idx];
        h[idx] = v;
        vv[i] = v;
    }
    // fused node-LN + ReLU -> r  (each half reduces its own rows over its own 2 waves)
    __shared__ float rs[2][2][4], rs2[2][2][4];
    int w2 = (tid >> 6) & 1;       // wave within half
#pragma unroll
    for (int i = 0; i < 4; i++) {
        float ss = vv[i], ss2 = vv[i] * vv[i];
#pragma unroll
        for (int off = 32; off; off >>= 1) { ss += __shfl_xor(ss, off); ss2 += __shfl_xor(ss2, off); }
        if ((tid & 63) == 0) { rs[half][w2][i] = ss; rs2[half][w2][i] = ss2; }
    }
    __syncthreads();
    float gc = lgp[o], bc = lbp[o];
#pragma unroll
    for (int i = 0; i < 4; i++) {
        float S = rs[half][0][i] + rs[half][1][i];
        float S2 = rs2[half][0][i] + rs2[half][1][i];
        float mn = S * (1.f / H);
        float vr = S2 * (1.f / H) - mn * mn;
        float inv = rsqrtf(vr + EPS_LN);
        float ov = (vv[i] - mn) * inv * gc + bc;
        r[(size_t)(n0 + rb + i) * H + o] = fmaxf(ov, 0.f);
    }
}

// ---------- out = r @ Wout + bout ----------
__global__ void __launch_bounds__(128) mmout_k(const float* __restrict__ r,
    const float* __restrict__ Wout, const float* __restrict__ bout,
    float* __restrict__ out) {
    int nb = blockIdx.x, o = threadIdx.x;
    int n0 = nb * TNO;
    __shared__ float a[TNO][H];
    for (int t = o; t < TNO * H; t += 128) ((float*)a)[t] = r[(size_t)n0 * H + t];
    __syncthreads();
    if (o < YD) {
        float acc[TNO];
#pragma unroll
        for (int i = 0; i < TNO; i++) acc[i] = 0.f;
        for (int k = 0; k < H; k++) {
            float w = Wout[k * YD + o];
#pragma unroll
            for (int i = 0; i < TNO; i++) acc[i] = fmaf(a[i][k], w, acc[i]);
        }
        float bo = bout[o];
#pragma unroll
        for (int i = 0; i < TNO; i++) out[(size_t)(n0 + i) * YD + o] = acc[i] + bo;
    }
}

extern "C" void kernel_launch(void* const* d_in, const int* in_sizes, int n_in,
                              void* d_out, int out_size, void* d_ws, size_t ws_size,
                              hipStream_t stream) {
    const float* x    = (const float*)d_in[0];
    const int*   ei   = (const int*)d_in[1];
    const float* eattr= (const float*)d_in[2];
    const float* Wn   = (const float*)d_in[3];
    const float* bn   = (const float*)d_in[4];
    const float* We   = (const float*)d_in[5];
    const float* be   = (const float*)d_in[6];
    const float* t    = (const float*)d_in[7];
    const float* W1   = (const float*)d_in[8];
    const float* b1   = (const float*)d_in[9];
    const float* g1   = (const float*)d_in[10];
    const float* bt1  = (const float*)d_in[11];
    const float* W2   = (const float*)d_in[12];
    const float* b2   = (const float*)d_in[13];
    const float* lng  = (const float*)d_in[14];
    const float* lnb  = (const float*)d_in[15];
    const float* Wout = (const float*)d_in[16];
    const float* bout = (const float*)d_in[17];
    float* out = (float*)d_out;

    const int* src = ei;        // edge_index[0]
    const int* dst = ei + NE;   // edge_index[1]

    char* ws = (char*)d_ws;
    size_t off = 0;
    auto alloc = [&](size_t bytes) -> char* {
        char* p = ws + off;
        off += (bytes + 255) & ~(size_t)255;
        return p;
    };
    int*      counts = (int*)alloc((size_t)NN * 4);
    int*      fill   = (int*)alloc((size_t)NN * 4);
    int*      rowptr = (int*)alloc((size_t)(NN + 1) * 4);
    int*      perm   = (int*)alloc((size_t)NE * 4);
    int*      srcs   = (int*)alloc((size_t)NE * 4);
    _Float16* eacsr  = (_Float16*)alloc((size_t)NE * ED * 2);  // 10 MB fp16
    float*    h      = (float*)alloc((size_t)NN * H * 4);
    float*    r      = (float*)alloc((size_t)NN * H * 4);
    float*    agg    = (float*)alloc((size_t)NN * H * 4);
    float*    y1     = (float*)alloc((size_t)NN * H2 * 4);
    float*    part   = (float*)alloc((size_t)NB1 * 2 * 4);
    (void)ws_size; (void)in_sizes; (void)n_in; (void)out_size;

    hipMemsetAsync(counts, 0, (size_t)NN * 4, stream);
    hipMemsetAsync(fill,   0, (size_t)NN * 4, stream);

    hist_k<<<(NE + 255) / 256, 256, 0, stream>>>(dst, counts);
    scan_k<<<1, 1024, 0, stream>>>(counts, rowptr);
    scatter_k<<<(NE + 255) / 256, 256, 0, stream>>>(dst, rowptr, fill, perm);
    pack_k<<<(NE + 255) / 256, 256, 0, stream>>>(perm, src, eattr, srcs, eacsr);
    node_enc_k<<<NN, H, 0, stream>>>(x, Wn, bn, h);

    for (int i = 0; i < NL; i++) {
        const float* cin = (i == 0) ? h : r;
        edge_agg_k<<<NN, H, 0, stream>>>(cin, rowptr, srcs, eacsr, We, be, t, i, agg);
        mm1_k<<<NB1, 256, 0, stream>>>(agg, W1 + (size_t)i * H * H2, b1 + i * H2, y1, part);
        int nx = (i == NL - 1) ? 0 : (i + 1);  // next node-LN params (final uses layer 0's)
        mm2_k<<<NB1, 256, 0, stream>>>(y1, g1 + i * H2, bt1 + i * H2,
                                       W2 + (size_t)i * H2 * H, b2 + i * H, part, h,
                                       lng + nx * H, lnb + nx * H, r, (i == 0) ? 1 : 0);
    }
    mmout_k<<<NBO, 128, 0, stream>>>(r, Wout, bout, out);
}